// Round 23
// baseline (196.164 us; speedup 1.0000x reference)
//
#include <hip/hip_runtime.h>
#include <hip/hip_bf16.h>

// Problem constants
#define L_SEQ 2048
#define BATCH 4
#define DMODEL 1024
#define NHEAD 16
#define HDIM 64

typedef short bf16x8 __attribute__((ext_vector_type(8)));
typedef float f32x4 __attribute__((ext_vector_type(4)));
typedef unsigned short us4 __attribute__((ext_vector_type(4)));
typedef unsigned int u32x2 __attribute__((ext_vector_type(2)));

#define MFMA(a, b, c) __builtin_amdgcn_mfma_f32_16x16x32_bf16((a), (b), (c), 0, 0, 0)

// official compiler conversion (pairs fuse to v_cvt_pk_bf16_f32); union
// extraction only — no inline asm, no vector bit_cast (session-convicted).
__device__ __forceinline__ unsigned short f2bf_hw(float f) {
  union { __hip_bfloat16 b; unsigned short u; } cv;
  cv.b = __float2bfloat16(f);
  return cv.u;
}

__device__ __forceinline__ void async16(const void* g, void* l) {
  __builtin_amdgcn_global_load_lds((const __attribute__((address_space(1))) void*)g,
                                   (__attribute__((address_space(3))) void*)l, 16, 0, 0);
}

// ---------------- fused prep kernel ----------------
// block ranges: [0,8192) f32->bf16 cvt of hs; [8192,11264) transpose Wqkv;
// [11264,12288) transpose Wout; [12288,12544) rope cos/sin tables.

__device__ __forceinline__ void transpose_body(const float* __restrict__ in,
                                               unsigned short* __restrict__ out,
                                               int R, int C, int t, int bw,
                                               float (*sm)[33]) {
  int tx = threadIdx.x & 31, ty = threadIdx.x >> 5;  // (32,8)
  int c0 = (t % bw) * 32, r0 = (t / bw) * 32;
#pragma unroll
  for (int j = 0; j < 4; ++j) sm[ty + 8 * j][tx] = in[(r0 + ty + 8 * j) * C + c0 + tx];
  __syncthreads();
#pragma unroll
  for (int j = 0; j < 4; ++j) out[(c0 + ty + 8 * j) * R + r0 + tx] = f2bf_hw(sm[tx][ty + 8 * j]);
}

__global__ void k_prep(const float* __restrict__ hs, unsigned short* __restrict__ hs16,
                       const float* __restrict__ Wqkv, unsigned short* __restrict__ WqkvT,
                       const float* __restrict__ Wout, unsigned short* __restrict__ WoutT,
                       const float* __restrict__ rp, float* __restrict__ ct,
                       float* __restrict__ st) {
  __shared__ float sm[32][33];
  const int b = blockIdx.x, tid = threadIdx.x;
  if (b < 8192) {
    int i = (b * 256 + tid) * 4;
    float4 v = *(const float4*)(hs + i);
    us4 o;
    o.x = f2bf_hw(v.x); o.y = f2bf_hw(v.y); o.z = f2bf_hw(v.z); o.w = f2bf_hw(v.w);
    *(us4*)(hs16 + i) = o;
  } else if (b < 11264) {
    transpose_body(Wqkv, WqkvT, 1024, 3072, b - 8192, 96, sm);
  } else if (b < 12288) {
    transpose_body(Wout, WoutT, 1024, 1024, b - 11264, 32, sm);
  } else {
    int i = (b - 12288) * 256 + tid;  // 65536 = 2048*32
    float a = rp[i];
    ct[i] = cosf(a);
    st[i] = sinf(a);
  }
}

// ---------------- QKV GEMM + bias + RoPE + transpose-scatter ----------------
// Q section is pre-scaled by 0.125 (1/sqrt(Hd)) so attention uses __expf(acc)
// directly. 1-D grid 1536 with XCD-chunked swizzle: xcd=id&7, j=id>>3,
// x = xcd + 8*(j>>6) (n-tile), y = j&63 (m-tile) — the 64 m-blocks sharing
// one B-panel land on ONE XCD -> B L2-resident (3 panels x 256 KB per XCD).
// Bijective: 8 x 3 x 64 = 1536. NO setprio (m190: hurts lockstep GEMMs).
__global__ __launch_bounds__(256, 2) void k_qkv_gemm(
    const unsigned short* __restrict__ A, const unsigned short* __restrict__ BT,
    const float* __restrict__ bias, const float* __restrict__ cost,
    const float* __restrict__ sint, unsigned short* __restrict__ Qg,
    unsigned short* __restrict__ Kg, unsigned short* __restrict__ Vg) {
  __shared__ __align__(16) unsigned short As[128 * 32];
  __shared__ __align__(16) unsigned short Bs[128 * 32];
  __shared__ float cs[1024], ss[1024];

  const int tid = threadIdx.x, lane = tid & 63, w = tid >> 6;
  const int wr = w >> 1, wc = w & 1;
  const int id = blockIdx.x;
  const int xcd = id & 7, j = id >> 3;
  const int bx = xcd + 8 * (j >> 6);   // n-tile 0..23
  const int by = j & 63;               // m-tile 0..63
  const int m0 = by * 128, n0 = bx * 128;
  const int c = lane & 15, g = lane >> 4;
  const bool dorope = (n0 < 2048);

  if (dorope) {
    const int l0 = m0 >> 2;
    *(float4*)(cs + tid * 4) = *(const float4*)(cost + l0 * 32 + tid * 4);
    *(float4*)(ss + tid * 4) = *(const float4*)(sint + l0 * 32 + tid * 4);
  }

  f32x4 acc[4][4] = {};
  for (int kt = 0; kt < 32; ++kt) {
    const int k0 = kt * 32;
    __syncthreads();
#pragma unroll
    for (int i = 0; i < 2; ++i) {
      int ch = i * 256 + tid;
      async16(A + (m0 + (ch >> 2)) * 1024 + k0 + (ch & 3) * 8, (char*)As + ch * 16);
      async16(BT + (n0 + (ch >> 2)) * 1024 + k0 + (ch & 3) * 8, (char*)Bs + ch * 16);
    }
    __syncthreads();
    bf16x8 a[4], b[4];
#pragma unroll
    for (int mf = 0; mf < 4; ++mf)
      a[mf] = *(const bf16x8*)&As[(wr * 64 + mf * 16 + c) * 32 + g * 8];
#pragma unroll
    for (int nf = 0; nf < 4; ++nf)
      b[nf] = *(const bf16x8*)&Bs[(wc * 64 + nf * 16 + c) * 32 + g * 8];
#pragma unroll
    for (int mf = 0; mf < 4; ++mf)
#pragma unroll
      for (int nf = 0; nf < 4; ++nf) acc[mf][nf] = MFMA(a[mf], b[nf], acc[mf][nf]);
  }

  const int nbase = n0 + wc * 64;
  const int sec = nbase >> 10;
  const int h = (nbase & 1023) >> 6;
  unsigned short* outp = (sec == 0) ? Qg : ((sec == 1) ? Kg : Vg);
  const float qscale = (sec == 0) ? 0.125f : 1.0f;
  float bv[4];
#pragma unroll
  for (int nf = 0; nf < 4; ++nf) bv[nf] = bias[nbase + nf * 16 + c];

#pragma unroll
  for (int mf = 0; mf < 4; ++mf) {
    const int l_loc = wr * 16 + mf * 4 + g;
    const int l = (m0 >> 2) + l_loc;
    float c1 = 0.f, s1 = 0.f, c2 = 0.f, s2 = 0.f;
    if (sec < 2) {
      c1 = cs[l_loc * 32 + c];      s1 = ss[l_loc * 32 + c];
      c2 = cs[l_loc * 32 + c + 16]; s2 = ss[l_loc * 32 + c + 16];
    }
#pragma unroll
    for (int r = 0; r < 4; ++r) {
      const int row = m0 + wr * 64 + mf * 16 + g * 4 + r;
      const int bb = row & 3;
      float x0 = acc[mf][0][r] + bv[0];
      float x1 = acc[mf][1][r] + bv[1];
      float x2 = acc[mf][2][r] + bv[2];
      float x3 = acc[mf][3][r] + bv[3];
      float y0, y1, y2, y3;
      if (sec < 2) {
        y0 = (x0 * c1 - x2 * s1) * qscale;
        y1 = (x1 * c2 - x3 * s2) * qscale;
        y2 = (x2 * c1 + x0 * s1) * qscale;
        y3 = (x3 * c2 + x1 * s2) * qscale;
      } else { y0 = x0; y1 = x1; y2 = x2; y3 = x3; }
      unsigned short* dst = outp + ((bb * 16 + h) * 2048 + l) * 64;
      dst[c] = f2bf_hw(y0); dst[c + 16] = f2bf_hw(y1);
      dst[c + 32] = f2bf_hw(y2); dst[c + 48] = f2bf_hw(y3);
    }
  }
}

// ---------------- flash attention v23 ----------------
// = R22 (passing, 84.2 us) with the setprio region EXTENDED: one prio-1 span
// from QK^T through softmax-exp to end of PV (was two spans with prio 0 over
// the exp block). The exp chain is this wave's serial VALU hog; holding
// priority lets it complete while the co-resident block's waves fill staging.
__global__ __launch_bounds__(256, 2) void k_attn(
    const unsigned short* __restrict__ Qg, const unsigned short* __restrict__ Kg,
    const unsigned short* __restrict__ Vg, unsigned short* __restrict__ Og) {
  __shared__ __align__(16) unsigned short Ks[2][64 * 64];   // 16 KB, XOR-swizzled
  __shared__ __align__(16) unsigned int Vt[64 * 36];        // 9 KB  [d][kp] u32, k-permuted

  const int tid = threadIdx.x, lane = tid & 63, w = tid >> 6;
  const int bh = blockIdx.x & 63;         // id%8 = bh%8 -> all q-tiles of a bh on one XCD
  const int qt = blockIdx.x >> 6;         // 0..7
  const int q0 = qt * 256 + w * 64;
  const size_t base = (size_t)bh * (2048 * 64);
  const int c = lane & 15, g = lane >> 4;

  // V staging: thread loads global keys 4T..4T+3 (T=tid&15) at d=vd0..+3 and
  // writes the two u32 pairs to permuted slots {vkp0, vkp0+1}:
  //   gk = 32s'+16kf'+4gg+r  ->  u32 slot = 16s' + 4gg + 2kf' + r/2
  const int vd0 = (tid >> 4) * 4;     // 0..60
  const int T = tid & 15;
  const int vkey0 = T * 4;            // global key base
  const int vkp0 = 16 * (T >> 3) + 4 * (T & 3) + 2 * ((T >> 2) & 1);

  const short one_bf = 0x3F80;
  const bf16x8 onesv = {one_bf, one_bf, one_bf, one_bf, one_bf, one_bf, one_bf, one_bf};

  // Q fragments (4 qi x 2 s)
  bf16x8 qf[4][2];
#pragma unroll
  for (int qi = 0; qi < 4; ++qi)
#pragma unroll
    for (int s = 0; s < 2; ++s)
      qf[qi][s] = *(const bf16x8*)(Qg + base + (q0 + qi * 16 + c) * 64 + 32 * s + 8 * g);

  f32x4 po[4][4] = {};
  f32x4 psum[4] = {};

  // ---- prologue: V(0) -> regs, issue K(0) -> Ks[0] (drains at barrier A, iter 0) ----
  u32x2 rv[4];
#pragma unroll
  for (int i = 0; i < 4; ++i)
    rv[i] = *(const u32x2*)(Vg + base + (vkey0 + i) * 64 + vd0);
#pragma unroll
  for (int i = 0; i < 2; ++i) {
    int p = i * 256 + tid;
    int key = p >> 3;
    int cc = (p & 7) ^ (key & 7);
    async16(Kg + base + key * 64 + cc * 8, (char*)Ks[0] + p * 16);
  }

  int buf = 0;
  for (int kv = 0; kv < 32; ++kv) {
    const bool pre = (kv < 31);
    // ---- write this tile's V (from regs) into single Vt (permuted slots) ----
#pragma unroll
    for (int t = 0; t < 4; ++t) {
      unsigned sel = (t & 1) ? 0x07060302u : 0x05040100u;
      unsigned w0 = __builtin_amdgcn_perm(rv[1][t >> 1], rv[0][t >> 1], sel);
      unsigned w1 = __builtin_amdgcn_perm(rv[3][t >> 1], rv[2][t >> 1], sel);
      *(u32x2*)&Vt[(vd0 + t) * 36 + vkp0] = u32x2{w0, w1};
    }
    // ---- issue next-tile V loads NOW (rv dead after the write above) ----
    if (pre) {
      const int nk = (kv + 1) * 64;
#pragma unroll
      for (int i = 0; i < 4; ++i)
        rv[i] = *(const u32x2*)(Vg + base + (nk + vkey0 + i) * 64 + vd0);
    }
    __syncthreads();  // A: Vt visible to all; K(kv) drained into Ks[buf]

    if (pre) {  // prefetch next tile K -> Ks[buf^1] (in flight until barrier B)
      const int nk = (kv + 1) * 64;
#pragma unroll
      for (int i = 0; i < 2; ++i) {
        int p = i * 256 + tid;
        int key = p >> 3;
        int cc = (p & 7) ^ (key & 7);
        async16(Kg + base + (nk + key) * 64 + cc * 8, (char*)Ks[buf ^ 1] + p * 16);
      }
    }

    // ---- QK^T: acc[qi][kf] rows=key(kf*16+g*4+r), col=q(c) ----
    f32x4 acc[4][4] = {};
    __builtin_amdgcn_s_setprio(1);
#pragma unroll
    for (int s = 0; s < 2; ++s) {
      bf16x8 ka[4];
#pragma unroll
      for (int kf = 0; kf < 4; ++kf) {
        int key = kf * 16 + c;
        int off = (key * 64 + 32 * s + 8 * g) * 2;
        off ^= (key & 7) << 4;
        ka[kf] = *(const bf16x8*)((const char*)Ks[buf] + off);
      }
#pragma unroll
      for (int kf = 0; kf < 4; ++kf)
#pragma unroll
        for (int qi = 0; qi < 4; ++qi)
          acc[qi][kf] = MFMA(ka[kf], qf[qi][s], acc[qi][kf]);
    }

    // ---- softmax-lite: P = __expf(acc); pa elementwise via HW cvt (pairs fuse) ----
    // pa[qi][s] element e holds P[key = 32s + 16*(e>>2) + 4g + (e&3)][q=c]
    // = acc[qi][2s + (e>>2)] reg (e&3)  -- matches the permuted-V key function.
    bf16x8 pa[4][2];
#pragma unroll
    for (int qi = 0; qi < 4; ++qi) {
#pragma unroll
      for (int kf = 0; kf < 4; ++kf) {
#pragma unroll
        for (int r = 0; r < 4; ++r) {
          float p = __expf(acc[qi][kf][r]);
          pa[qi][kf >> 1][(kf & 1) * 4 + r] = (short)f2bf_hw(p);
        }
      }
    }

    // ---- PV + row-sum MFMA: po[qi][df] rows=q(g*4+r), col=d(c) ----
#pragma unroll
    for (int s = 0; s < 2; ++s) {
#pragma unroll
      for (int df = 0; df < 4; ++df) {
        bf16x8 vb = *(const bf16x8*)&Vt[(df * 16 + c) * 36 + 16 * s + 4 * g];
#pragma unroll
        for (int qi = 0; qi < 4; ++qi)
          po[qi][df] = MFMA(pa[qi][s], vb, po[qi][df]);
      }
#pragma unroll
      for (int qi = 0; qi < 4; ++qi)
        psum[qi] = MFMA(pa[qi][s], onesv, psum[qi]);
    }
    __builtin_amdgcn_s_setprio(0);

    __syncthreads();  // B: all PV reads of Vt done before next top-of-loop write; K(kv+1) drained
    buf ^= 1;
  }

  // ---- epilogue: O = po / psum (psum already in po register layout) ----
#pragma unroll
  for (int qi = 0; qi < 4; ++qi) {
    float il[4];
#pragma unroll
    for (int r = 0; r < 4; ++r) il[r] = 1.0f / psum[qi][r];
#pragma unroll
    for (int df = 0; df < 4; ++df)
#pragma unroll
      for (int r = 0; r < 4; ++r) {
        int q = q0 + qi * 16 + g * 4 + r;
        Og[base + q * 64 + df * 16 + c] = f2bf_hw(po[qi][df][r] * il[r]);
      }
  }
}

// ---------------- output projection ----------------
__global__ __launch_bounds__(256, 2) void k_proj(
    const unsigned short* __restrict__ Og, const unsigned short* __restrict__ BT,
    const float* __restrict__ bias, float* __restrict__ out) {
  __shared__ __align__(16) unsigned short As[128 * 32];
  __shared__ __align__(16) unsigned short Bs[128 * 32];

  const int tid = threadIdx.x, lane = tid & 63, w = tid >> 6;
  const int wr = w >> 1, wc = w & 1;
  const int m0 = blockIdx.y * 128, n0 = blockIdx.x * 128;
  const int c = lane & 15, g = lane >> 4;

  f32x4 acc[4][4] = {};
  for (int kt = 0; kt < 32; ++kt) {
    const int k0 = kt * 32;
    __syncthreads();
#pragma unroll
    for (int i = 0; i < 2; ++i) {
      int ch = i * 256 + tid;
      int m = m0 + (ch >> 2);
      int kcol = k0 + (ch & 3) * 8;
      int l = m >> 2, bb = m & 3, h = kcol >> 6, hd = kcol & 63;
      async16(Og + ((bb * 16 + h) * 2048 + l) * 64 + hd, (char*)As + ch * 16);
      async16(BT + (n0 + (ch >> 2)) * 1024 + kcol, (char*)Bs + ch * 16);
    }
    __syncthreads();
    bf16x8 a[4], b[4];
#pragma unroll
    for (int mf = 0; mf < 4; ++mf)
      a[mf] = *(const bf16x8*)&As[(wr * 64 + mf * 16 + c) * 32 + g * 8];
#pragma unroll
    for (int nf = 0; nf < 4; ++nf)
      b[nf] = *(const bf16x8*)&Bs[(wc * 64 + nf * 16 + c) * 32 + g * 8];
#pragma unroll
    for (int mf = 0; mf < 4; ++mf)
#pragma unroll
      for (int nf = 0; nf < 4; ++nf) acc[mf][nf] = MFMA(a[mf], b[nf], acc[mf][nf]);
  }

  float bv[4];
#pragma unroll
  for (int nf = 0; nf < 4; ++nf) bv[nf] = bias[n0 + wc * 64 + nf * 16 + c];
#pragma unroll
  for (int mf = 0; mf < 4; ++mf)
#pragma unroll
    for (int r = 0; r < 4; ++r) {
      int m = m0 + wr * 64 + mf * 16 + g * 4 + r;
      float* dst = out + m * 1024 + n0 + wc * 64;
      dst[c] = acc[mf][0][r] + bv[0];
      dst[c + 16] = acc[mf][1][r] + bv[1];
      dst[c + 32] = acc[mf][2][r] + bv[2];
      dst[c + 48] = acc[mf][3][r] + bv[3];
    }
}

// ---------------- launch ----------------

extern "C" void kernel_launch(void* const* d_in, const int* in_sizes, int n_in,
                              void* d_out, int out_size, void* d_ws, size_t ws_size,
                              hipStream_t stream) {
  const float* hs = (const float*)d_in[0];
  const float* rp = (const float*)d_in[1];
  const float* Wqkv = (const float*)d_in[2];
  const float* bqkv = (const float*)d_in[3];
  const float* Wout = (const float*)d_in[4];
  const float* bout = (const float*)d_in[5];
  float* out = (float*)d_out;
  char* ws = (char*)d_ws;

  unsigned short* hs16 = (unsigned short*)(ws + 0);           // 16 MB (reused as Og)
  unsigned short* WqkvT = (unsigned short*)(ws + 16777216);   // 6 MB
  unsigned short* WoutT = (unsigned short*)(ws + 23068672);   // 2 MB
  float* cost = (float*)(ws + 25165824);                      // 256 KB
  float* sint = (float*)(ws + 25427968);                      // 256 KB
  unsigned short* Qg = (unsigned short*)(ws + 25690112);      // 16 MB
  unsigned short* Kg = (unsigned short*)(ws + 42467328);      // 16 MB
  unsigned short* Vg = (unsigned short*)(ws + 59244544);      // 16 MB
  unsigned short* Og = hs16;

  k_prep<<<12544, 256, 0, stream>>>(hs, hs16, Wqkv, WqkvT, Wout, WoutT, rp, cost, sint);
  k_qkv_gemm<<<1536, 256, 0, stream>>>(hs16, WqkvT, bqkv, cost, sint, Qg, Kg, Vg);
  k_attn<<<512, 256, 0, stream>>>(Qg, Kg, Vg, Og);
  k_proj<<<dim3(8, 64), 256, 0, stream>>>(Og, WoutT, bout, out);
}

// Round 24
// 186.957 us; speedup vs baseline: 1.0492x; 1.0492x over previous
//
#include <hip/hip_runtime.h>
#include <hip/hip_bf16.h>

// Problem constants
#define L_SEQ 2048
#define BATCH 4
#define DMODEL 1024
#define NHEAD 16
#define HDIM 64

typedef short bf16x8 __attribute__((ext_vector_type(8)));
typedef float f32x4 __attribute__((ext_vector_type(4)));
typedef unsigned short us4 __attribute__((ext_vector_type(4)));
typedef unsigned int u32x2 __attribute__((ext_vector_type(2)));

#define MFMA(a, b, c) __builtin_amdgcn_mfma_f32_16x16x32_bf16((a), (b), (c), 0, 0, 0)

// official compiler conversion (pairs fuse to v_cvt_pk_bf16_f32); union
// extraction only — no inline asm, no vector bit_cast (session-convicted).
__device__ __forceinline__ unsigned short f2bf_hw(float f) {
  union { __hip_bfloat16 b; unsigned short u; } cv;
  cv.b = __float2bfloat16(f);
  return cv.u;
}

__device__ __forceinline__ void async16(const void* g, void* l) {
  __builtin_amdgcn_global_load_lds((const __attribute__((address_space(1))) void*)g,
                                   (__attribute__((address_space(3))) void*)l, 16, 0, 0);
}

// ---------------- fused prep kernel ----------------
// block ranges: [0,8192) f32->bf16 cvt of hs; [8192,11264) transpose Wqkv;
// [11264,12288) transpose Wout; [12288,12544) rope cos/sin tables.

__device__ __forceinline__ void transpose_body(const float* __restrict__ in,
                                               unsigned short* __restrict__ out,
                                               int R, int C, int t, int bw,
                                               float (*sm)[33]) {
  int tx = threadIdx.x & 31, ty = threadIdx.x >> 5;  // (32,8)
  int c0 = (t % bw) * 32, r0 = (t / bw) * 32;
#pragma unroll
  for (int j = 0; j < 4; ++j) sm[ty + 8 * j][tx] = in[(r0 + ty + 8 * j) * C + c0 + tx];
  __syncthreads();
#pragma unroll
  for (int j = 0; j < 4; ++j) out[(c0 + ty + 8 * j) * R + r0 + tx] = f2bf_hw(sm[tx][ty + 8 * j]);
}

__global__ void k_prep(const float* __restrict__ hs, unsigned short* __restrict__ hs16,
                       const float* __restrict__ Wqkv, unsigned short* __restrict__ WqkvT,
                       const float* __restrict__ Wout, unsigned short* __restrict__ WoutT,
                       const float* __restrict__ rp, float* __restrict__ ct,
                       float* __restrict__ st) {
  __shared__ float sm[32][33];
  const int b = blockIdx.x, tid = threadIdx.x;
  if (b < 8192) {
    int i = (b * 256 + tid) * 4;
    float4 v = *(const float4*)(hs + i);
    us4 o;
    o.x = f2bf_hw(v.x); o.y = f2bf_hw(v.y); o.z = f2bf_hw(v.z); o.w = f2bf_hw(v.w);
    *(us4*)(hs16 + i) = o;
  } else if (b < 11264) {
    transpose_body(Wqkv, WqkvT, 1024, 3072, b - 8192, 96, sm);
  } else if (b < 12288) {
    transpose_body(Wout, WoutT, 1024, 1024, b - 11264, 32, sm);
  } else {
    int i = (b - 12288) * 256 + tid;  // 65536 = 2048*32
    float a = rp[i];
    ct[i] = cosf(a);
    st[i] = sinf(a);
  }
}

// ---------------- QKV GEMM + bias + RoPE + transpose-scatter ----------------
// Q section is pre-scaled by 0.125 (1/sqrt(Hd)) so attention uses __expf(acc)
// directly (__expf = v_mul(log2e) + v_exp, the fast path; libm exp2f is an
// ocml call and SLOWER — measured R18: +21 us). NO setprio here (m190) and
// dim3(24,64) grid (R23's XCD swizzle regressed — reverted).
__global__ __launch_bounds__(256, 2) void k_qkv_gemm(
    const unsigned short* __restrict__ A, const unsigned short* __restrict__ BT,
    const float* __restrict__ bias, const float* __restrict__ cost,
    const float* __restrict__ sint, unsigned short* __restrict__ Qg,
    unsigned short* __restrict__ Kg, unsigned short* __restrict__ Vg) {
  __shared__ __align__(16) unsigned short As[128 * 32];
  __shared__ __align__(16) unsigned short Bs[128 * 32];
  __shared__ float cs[1024], ss[1024];

  const int tid = threadIdx.x, lane = tid & 63, w = tid >> 6;
  const int wr = w >> 1, wc = w & 1;
  const int m0 = blockIdx.y * 128, n0 = blockIdx.x * 128;
  const int c = lane & 15, g = lane >> 4;
  const bool dorope = (n0 < 2048);

  if (dorope) {
    const int l0 = m0 >> 2;
    *(float4*)(cs + tid * 4) = *(const float4*)(cost + l0 * 32 + tid * 4);
    *(float4*)(ss + tid * 4) = *(const float4*)(sint + l0 * 32 + tid * 4);
  }

  f32x4 acc[4][4] = {};
  for (int kt = 0; kt < 32; ++kt) {
    const int k0 = kt * 32;
    __syncthreads();
#pragma unroll
    for (int i = 0; i < 2; ++i) {
      int ch = i * 256 + tid;
      async16(A + (m0 + (ch >> 2)) * 1024 + k0 + (ch & 3) * 8, (char*)As + ch * 16);
      async16(BT + (n0 + (ch >> 2)) * 1024 + k0 + (ch & 3) * 8, (char*)Bs + ch * 16);
    }
    __syncthreads();
    bf16x8 a[4], b[4];
#pragma unroll
    for (int mf = 0; mf < 4; ++mf)
      a[mf] = *(const bf16x8*)&As[(wr * 64 + mf * 16 + c) * 32 + g * 8];
#pragma unroll
    for (int nf = 0; nf < 4; ++nf)
      b[nf] = *(const bf16x8*)&Bs[(wc * 64 + nf * 16 + c) * 32 + g * 8];
#pragma unroll
    for (int mf = 0; mf < 4; ++mf)
#pragma unroll
      for (int nf = 0; nf < 4; ++nf) acc[mf][nf] = MFMA(a[mf], b[nf], acc[mf][nf]);
  }

  const int nbase = n0 + wc * 64;
  const int sec = nbase >> 10;
  const int h = (nbase & 1023) >> 6;
  unsigned short* outp = (sec == 0) ? Qg : ((sec == 1) ? Kg : Vg);
  const float qscale = (sec == 0) ? 0.125f : 1.0f;
  float bv[4];
#pragma unroll
  for (int nf = 0; nf < 4; ++nf) bv[nf] = bias[nbase + nf * 16 + c];

#pragma unroll
  for (int mf = 0; mf < 4; ++mf) {
    const int l_loc = wr * 16 + mf * 4 + g;
    const int l = (m0 >> 2) + l_loc;
    float c1 = 0.f, s1 = 0.f, c2 = 0.f, s2 = 0.f;
    if (sec < 2) {
      c1 = cs[l_loc * 32 + c];      s1 = ss[l_loc * 32 + c];
      c2 = cs[l_loc * 32 + c + 16]; s2 = ss[l_loc * 32 + c + 16];
    }
#pragma unroll
    for (int r = 0; r < 4; ++r) {
      const int row = m0 + wr * 64 + mf * 16 + g * 4 + r;
      const int bb = row & 3;
      float x0 = acc[mf][0][r] + bv[0];
      float x1 = acc[mf][1][r] + bv[1];
      float x2 = acc[mf][2][r] + bv[2];
      float x3 = acc[mf][3][r] + bv[3];
      float y0, y1, y2, y3;
      if (sec < 2) {
        y0 = (x0 * c1 - x2 * s1) * qscale;
        y1 = (x1 * c2 - x3 * s2) * qscale;
        y2 = (x2 * c1 + x0 * s1) * qscale;
        y3 = (x3 * c2 + x1 * s2) * qscale;
      } else { y0 = x0; y1 = x1; y2 = x2; y3 = x3; }
      unsigned short* dst = outp + ((bb * 16 + h) * 2048 + l) * 64;
      dst[c] = f2bf_hw(y0); dst[c + 16] = f2bf_hw(y1);
      dst[c + 32] = f2bf_hw(y2); dst[c + 48] = f2bf_hw(y3);
    }
  }
}

// ---------------- flash attention v24 = R22 exactly ----------------
// Best passing attn (84.2 us): 4 qi/wave ILP, single Vt, 2 barriers/tile,
// permuted-V slots, in-register pa via pair-fusing HW cvt, __expf fast exp,
// XCD-aware 1D grid, psum ones-MFMA, TWO setprio spans (R23's single
// extended span regressed +6 us — exp block must run at prio 0).
__global__ __launch_bounds__(256, 2) void k_attn(
    const unsigned short* __restrict__ Qg, const unsigned short* __restrict__ Kg,
    const unsigned short* __restrict__ Vg, unsigned short* __restrict__ Og) {
  __shared__ __align__(16) unsigned short Ks[2][64 * 64];   // 16 KB, XOR-swizzled
  __shared__ __align__(16) unsigned int Vt[64 * 36];        // 9 KB  [d][kp] u32, k-permuted

  const int tid = threadIdx.x, lane = tid & 63, w = tid >> 6;
  const int bh = blockIdx.x & 63;         // id%8 = bh%8 -> all q-tiles of a bh on one XCD
  const int qt = blockIdx.x >> 6;         // 0..7
  const int q0 = qt * 256 + w * 64;
  const size_t base = (size_t)bh * (2048 * 64);
  const int c = lane & 15, g = lane >> 4;

  // V staging: thread loads global keys 4T..4T+3 (T=tid&15) at d=vd0..+3 and
  // writes the two u32 pairs to permuted slots {vkp0, vkp0+1}:
  //   gk = 32s'+16kf'+4gg+r  ->  u32 slot = 16s' + 4gg + 2kf' + r/2
  const int vd0 = (tid >> 4) * 4;     // 0..60
  const int T = tid & 15;
  const int vkey0 = T * 4;            // global key base
  const int vkp0 = 16 * (T >> 3) + 4 * (T & 3) + 2 * ((T >> 2) & 1);

  const short one_bf = 0x3F80;
  const bf16x8 onesv = {one_bf, one_bf, one_bf, one_bf, one_bf, one_bf, one_bf, one_bf};

  // Q fragments (4 qi x 2 s)
  bf16x8 qf[4][2];
#pragma unroll
  for (int qi = 0; qi < 4; ++qi)
#pragma unroll
    for (int s = 0; s < 2; ++s)
      qf[qi][s] = *(const bf16x8*)(Qg + base + (q0 + qi * 16 + c) * 64 + 32 * s + 8 * g);

  f32x4 po[4][4] = {};
  f32x4 psum[4] = {};

  // ---- prologue: V(0) -> regs, issue K(0) -> Ks[0] (drains at barrier A, iter 0) ----
  u32x2 rv[4];
#pragma unroll
  for (int i = 0; i < 4; ++i)
    rv[i] = *(const u32x2*)(Vg + base + (vkey0 + i) * 64 + vd0);
#pragma unroll
  for (int i = 0; i < 2; ++i) {
    int p = i * 256 + tid;
    int key = p >> 3;
    int cc = (p & 7) ^ (key & 7);
    async16(Kg + base + key * 64 + cc * 8, (char*)Ks[0] + p * 16);
  }

  int buf = 0;
  for (int kv = 0; kv < 32; ++kv) {
    const bool pre = (kv < 31);
    // ---- write this tile's V (from regs) into single Vt (permuted slots) ----
#pragma unroll
    for (int t = 0; t < 4; ++t) {
      unsigned sel = (t & 1) ? 0x07060302u : 0x05040100u;
      unsigned w0 = __builtin_amdgcn_perm(rv[1][t >> 1], rv[0][t >> 1], sel);
      unsigned w1 = __builtin_amdgcn_perm(rv[3][t >> 1], rv[2][t >> 1], sel);
      *(u32x2*)&Vt[(vd0 + t) * 36 + vkp0] = u32x2{w0, w1};
    }
    // ---- issue next-tile V loads NOW (rv dead after the write above) ----
    if (pre) {
      const int nk = (kv + 1) * 64;
#pragma unroll
      for (int i = 0; i < 4; ++i)
        rv[i] = *(const u32x2*)(Vg + base + (nk + vkey0 + i) * 64 + vd0);
    }
    __syncthreads();  // A: Vt visible to all; K(kv) drained into Ks[buf]

    if (pre) {  // prefetch next tile K -> Ks[buf^1] (in flight until barrier B)
      const int nk = (kv + 1) * 64;
#pragma unroll
      for (int i = 0; i < 2; ++i) {
        int p = i * 256 + tid;
        int key = p >> 3;
        int cc = (p & 7) ^ (key & 7);
        async16(Kg + base + (nk + key) * 64 + cc * 8, (char*)Ks[buf ^ 1] + p * 16);
      }
    }

    // ---- QK^T: acc[qi][kf] rows=key(kf*16+g*4+r), col=q(c) ----
    f32x4 acc[4][4] = {};
    __builtin_amdgcn_s_setprio(1);
#pragma unroll
    for (int s = 0; s < 2; ++s) {
      bf16x8 ka[4];
#pragma unroll
      for (int kf = 0; kf < 4; ++kf) {
        int key = kf * 16 + c;
        int off = (key * 64 + 32 * s + 8 * g) * 2;
        off ^= (key & 7) << 4;
        ka[kf] = *(const bf16x8*)((const char*)Ks[buf] + off);
      }
#pragma unroll
      for (int kf = 0; kf < 4; ++kf)
#pragma unroll
        for (int qi = 0; qi < 4; ++qi)
          acc[qi][kf] = MFMA(ka[kf], qf[qi][s], acc[qi][kf]);
    }
    __builtin_amdgcn_s_setprio(0);

    // ---- softmax-lite: P = __expf(acc); pa elementwise via HW cvt (pairs fuse) ----
    // pa[qi][s] element e holds P[key = 32s + 16*(e>>2) + 4g + (e&3)][q=c]
    // = acc[qi][2s + (e>>2)] reg (e&3)  -- matches the permuted-V key function.
    bf16x8 pa[4][2];
#pragma unroll
    for (int qi = 0; qi < 4; ++qi) {
#pragma unroll
      for (int kf = 0; kf < 4; ++kf) {
#pragma unroll
        for (int r = 0; r < 4; ++r) {
          float p = __expf(acc[qi][kf][r]);
          pa[qi][kf >> 1][(kf & 1) * 4 + r] = (short)f2bf_hw(p);
        }
      }
    }

    // ---- PV + row-sum MFMA: po[qi][df] rows=q(g*4+r), col=d(c) ----
    __builtin_amdgcn_s_setprio(1);
#pragma unroll
    for (int s = 0; s < 2; ++s) {
#pragma unroll
      for (int df = 0; df < 4; ++df) {
        bf16x8 vb = *(const bf16x8*)&Vt[(df * 16 + c) * 36 + 16 * s + 4 * g];
#pragma unroll
        for (int qi = 0; qi < 4; ++qi)
          po[qi][df] = MFMA(pa[qi][s], vb, po[qi][df]);
      }
#pragma unroll
      for (int qi = 0; qi < 4; ++qi)
        psum[qi] = MFMA(pa[qi][s], onesv, psum[qi]);
    }
    __builtin_amdgcn_s_setprio(0);

    __syncthreads();  // B: all PV reads of Vt done before next top-of-loop write; K(kv+1) drained
    buf ^= 1;
  }

  // ---- epilogue: O = po / psum (psum already in po register layout) ----
#pragma unroll
  for (int qi = 0; qi < 4; ++qi) {
    float il[4];
#pragma unroll
    for (int r = 0; r < 4; ++r) il[r] = 1.0f / psum[qi][r];
#pragma unroll
    for (int df = 0; df < 4; ++df)
#pragma unroll
      for (int r = 0; r < 4; ++r) {
        int q = q0 + qi * 16 + g * 4 + r;
        Og[base + q * 64 + df * 16 + c] = f2bf_hw(po[qi][df][r] * il[r]);
      }
  }
}

// ---------------- output projection ----------------
__global__ __launch_bounds__(256, 2) void k_proj(
    const unsigned short* __restrict__ Og, const unsigned short* __restrict__ BT,
    const float* __restrict__ bias, float* __restrict__ out) {
  __shared__ __align__(16) unsigned short As[128 * 32];
  __shared__ __align__(16) unsigned short Bs[128 * 32];

  const int tid = threadIdx.x, lane = tid & 63, w = tid >> 6;
  const int wr = w >> 1, wc = w & 1;
  const int m0 = blockIdx.y * 128, n0 = blockIdx.x * 128;
  const int c = lane & 15, g = lane >> 4;

  f32x4 acc[4][4] = {};
  for (int kt = 0; kt < 32; ++kt) {
    const int k0 = kt * 32;
    __syncthreads();
#pragma unroll
    for (int i = 0; i < 2; ++i) {
      int ch = i * 256 + tid;
      int m = m0 + (ch >> 2);
      int kcol = k0 + (ch & 3) * 8;
      int l = m >> 2, bb = m & 3, h = kcol >> 6, hd = kcol & 63;
      async16(Og + ((bb * 16 + h) * 2048 + l) * 64 + hd, (char*)As + ch * 16);
      async16(BT + (n0 + (ch >> 2)) * 1024 + kcol, (char*)Bs + ch * 16);
    }
    __syncthreads();
    bf16x8 a[4], b[4];
#pragma unroll
    for (int mf = 0; mf < 4; ++mf)
      a[mf] = *(const bf16x8*)&As[(wr * 64 + mf * 16 + c) * 32 + g * 8];
#pragma unroll
    for (int nf = 0; nf < 4; ++nf)
      b[nf] = *(const bf16x8*)&Bs[(wc * 64 + nf * 16 + c) * 32 + g * 8];
#pragma unroll
    for (int mf = 0; mf < 4; ++mf)
#pragma unroll
      for (int nf = 0; nf < 4; ++nf) acc[mf][nf] = MFMA(a[mf], b[nf], acc[mf][nf]);
  }

  float bv[4];
#pragma unroll
  for (int nf = 0; nf < 4; ++nf) bv[nf] = bias[n0 + wc * 64 + nf * 16 + c];
#pragma unroll
  for (int mf = 0; mf < 4; ++mf)
#pragma unroll
    for (int r = 0; r < 4; ++r) {
      int m = m0 + wr * 64 + mf * 16 + g * 4 + r;
      float* dst = out + m * 1024 + n0 + wc * 64;
      dst[c] = acc[mf][0][r] + bv[0];
      dst[c + 16] = acc[mf][1][r] + bv[1];
      dst[c + 32] = acc[mf][2][r] + bv[2];
      dst[c + 48] = acc[mf][3][r] + bv[3];
    }
}

// ---------------- launch ----------------

extern "C" void kernel_launch(void* const* d_in, const int* in_sizes, int n_in,
                              void* d_out, int out_size, void* d_ws, size_t ws_size,
                              hipStream_t stream) {
  const float* hs = (const float*)d_in[0];
  const float* rp = (const float*)d_in[1];
  const float* Wqkv = (const float*)d_in[2];
  const float* bqkv = (const float*)d_in[3];
  const float* Wout = (const float*)d_in[4];
  const float* bout = (const float*)d_in[5];
  float* out = (float*)d_out;
  char* ws = (char*)d_ws;

  unsigned short* hs16 = (unsigned short*)(ws + 0);           // 16 MB (reused as Og)
  unsigned short* WqkvT = (unsigned short*)(ws + 16777216);   // 6 MB
  unsigned short* WoutT = (unsigned short*)(ws + 23068672);   // 2 MB
  float* cost = (float*)(ws + 25165824);                      // 256 KB
  float* sint = (float*)(ws + 25427968);                      // 256 KB
  unsigned short* Qg = (unsigned short*)(ws + 25690112);      // 16 MB
  unsigned short* Kg = (unsigned short*)(ws + 42467328);      // 16 MB
  unsigned short* Vg = (unsigned short*)(ws + 59244544);      // 16 MB
  unsigned short* Og = hs16;

  k_prep<<<12544, 256, 0, stream>>>(hs, hs16, Wqkv, WqkvT, Wout, WoutT, rp, cost, sint);
  k_qkv_gemm<<<dim3(24, 64), 256, 0, stream>>>(hs16, WqkvT, bqkv, cost, sint, Qg, Kg, Vg);
  k_attn<<<512, 256, 0, stream>>>(Qg, Kg, Vg, Og);
  k_proj<<<dim3(8, 64), 256, 0, stream>>>(Og, WoutT, bout, out);
}